// Round 1
// baseline (588.492 us; speedup 1.0000x reference)
//
#include <hip/hip_runtime.h>
#include <hip/hip_bf16.h>

#define T_TASKS 16
#define S_SUP   2048
#define Q_QRY   2048
#define D_IN    256
#define H_HID   512
#define D_EMB   128
#define N_WAY   64

// ---------------------------------------------------------------------------
// Embed: out[row] = relu(x[row] @ W1 + b1) @ W2 + b2
// One block of 256 threads handles 16 rows.
// ---------------------------------------------------------------------------
__global__ __launch_bounds__(256) void embed_kernel(
    const float* __restrict__ x, const float* __restrict__ W1,
    const float* __restrict__ b1, const float* __restrict__ W2,
    const float* __restrict__ b2, float* __restrict__ out)
{
    __shared__ float xs[16][D_IN];   // 16 KiB
    __shared__ float hs[16][H_HID];  // 32 KiB

    const int tid = threadIdx.x;
    const long rowbase = (long)blockIdx.x * 16;

    // stage x tile (16*256 floats = 1024 float4, 4 per thread)
    {
        const float4* xv = (const float4*)(x + rowbase * D_IN);
        float4* xsv = (float4*)(&xs[0][0]);
        #pragma unroll
        for (int i = 0; i < 4; ++i) xsv[tid + 256 * i] = xv[tid + 256 * i];
    }
    __syncthreads();

    // GEMM1: [16 x 256] @ [256 x 512] -> relu -> hs
    {
        const int tx = tid & 63;       // column group (8 cols, stride 64)
        const int ty = tid >> 6;       // row group (4 rows)
        float acc[4][8];
        #pragma unroll
        for (int j = 0; j < 8; ++j) {
            float bj = b1[tx + 64 * j];
            #pragma unroll
            for (int r = 0; r < 4; ++r) acc[r][j] = bj;
        }
        const float* w1p = W1 + tx;
        for (int k = 0; k < D_IN; ++k) {
            float xr[4];
            #pragma unroll
            for (int r = 0; r < 4; ++r) xr[r] = xs[ty * 4 + r][k];
            #pragma unroll
            for (int j = 0; j < 8; ++j) {
                float w = w1p[(long)k * H_HID + 64 * j];
                #pragma unroll
                for (int r = 0; r < 4; ++r) acc[r][j] += xr[r] * w;
            }
        }
        #pragma unroll
        for (int r = 0; r < 4; ++r)
            #pragma unroll
            for (int j = 0; j < 8; ++j)
                hs[ty * 4 + r][tx + 64 * j] = fmaxf(acc[r][j], 0.0f);
    }
    __syncthreads();

    // GEMM2: [16 x 512] @ [512 x 128] -> out
    {
        const int col = tid & 127;     // 0..127
        const int rg  = tid >> 7;      // 0..1 -> rows rg*8..rg*8+7
        float acc[8];
        float bc = b2[col];
        #pragma unroll
        for (int r = 0; r < 8; ++r) acc[r] = bc;
        for (int k = 0; k < H_HID; k += 4) {
            float w0 = W2[(long)(k + 0) * D_EMB + col];
            float w1 = W2[(long)(k + 1) * D_EMB + col];
            float w2 = W2[(long)(k + 2) * D_EMB + col];
            float w3 = W2[(long)(k + 3) * D_EMB + col];
            #pragma unroll
            for (int r = 0; r < 8; ++r) {
                const float4 h4 = *(const float4*)&hs[rg * 8 + r][k];
                acc[r] += h4.x * w0 + h4.y * w1 + h4.z * w2 + h4.w * w3;
            }
        }
        #pragma unroll
        for (int r = 0; r < 8; ++r)
            out[(rowbase + rg * 8 + r) * D_EMB + col] = acc[r];
    }
}

// ---------------------------------------------------------------------------
// Prototypes: block (t,c) gathers mean of se rows whose id == c.
// 128 threads, thread d owns dim d. Deterministic (no atomics).
// ---------------------------------------------------------------------------
__global__ __launch_bounds__(128) void proto_kernel(
    const float* __restrict__ se, const int* __restrict__ ids,
    float* __restrict__ protos)
{
    const int t = blockIdx.x >> 6;
    const int c = blockIdx.x & 63;
    const int d = threadIdx.x;

    const int* idrow = ids + t * S_SUP;
    const float* serow = se + (long)t * S_SUP * D_EMB;

    float acc = 0.0f;
    int cnt = 0;
    for (int s = 0; s < S_SUP; ++s) {
        if (idrow[s] == c) {
            acc += serow[(long)s * D_EMB + d];
            cnt++;
        }
    }
    float denom = (float)(cnt > 0 ? cnt : 1);
    protos[((long)t * N_WAY + c) * D_EMB + d] = acc / denom;
}

// ---------------------------------------------------------------------------
// Query: dist -> softmax -> pred -> squared error. Block = 256 thr (4 waves),
// handles 32 queries of one task. Protos of the task staged in LDS.
// ---------------------------------------------------------------------------
#define QPB 32

__global__ __launch_bounds__(256) void query_kernel(
    const float* __restrict__ qe, const float* __restrict__ qy,
    const float* __restrict__ protos, float* __restrict__ partials)
{
    __shared__ float ps[N_WAY][D_EMB + 1];  // padded stride 129 -> conflict-free
    __shared__ float qes[4][D_EMB];
    __shared__ float probs[4][N_WAY];
    __shared__ float wloss[4];

    const int tid  = threadIdx.x;
    const int t    = blockIdx.x >> 6;          // 64 blocks per task
    const int q0   = (blockIdx.x & 63) * QPB;
    const int wave = tid >> 6;
    const int lane = tid & 63;

    // stage protos[t]: 8192 floats, 32 per thread
    {
        const float* pt = protos + (long)t * N_WAY * D_EMB;
        #pragma unroll
        for (int i = 0; i < 32; ++i) {
            int idx = tid + 256 * i;
            ps[idx >> 7][idx & 127] = pt[idx];
        }
    }
    __syncthreads();

    float lossacc = 0.0f;

    for (int qi = wave; qi < QPB; qi += 4) {
        const long q = q0 + qi;
        const float* qrow = qe + ((long)t * Q_QRY + q) * D_EMB;

        qes[wave][lane]      = qrow[lane];
        qes[wave][lane + 64] = qrow[lane + 64];
        __syncthreads();

        // lane = class c: distance
        float s = 0.0f;
        #pragma unroll 16
        for (int d = 0; d < D_EMB; ++d) {
            float diff = qes[wave][d] - ps[lane][d];
            s += diff * diff;
        }
        float logit = -sqrtf(s);   // TEMPERATURE = 1

        // wave softmax over 64 lanes
        float m = logit;
        #pragma unroll
        for (int off = 32; off >= 1; off >>= 1) m = fmaxf(m, __shfl_xor(m, off));
        float e = __expf(logit - m);
        float sum = e;
        #pragma unroll
        for (int off = 32; off >= 1; off >>= 1) sum += __shfl_xor(sum, off);
        probs[wave][lane] = e / sum;
        __syncthreads();

        // lane = dim (d, d+64): pred + loss
        float pr0 = 0.0f, pr1 = 0.0f;
        #pragma unroll 16
        for (int c = 0; c < N_WAY; ++c) {
            float p = probs[wave][c];
            pr0 += p * ps[c][lane];
            pr1 += p * ps[c][lane + 64];
        }
        const float* yrow = qy + ((long)t * Q_QRY + q) * D_EMB;
        float d0 = pr0 - yrow[lane];
        float d1 = pr1 - yrow[lane + 64];
        lossacc += d0 * d0 + d1 * d1;
        __syncthreads();
    }

    // reduce lossacc: wave, then block
    #pragma unroll
    for (int off = 32; off >= 1; off >>= 1) lossacc += __shfl_xor(lossacc, off);
    if (lane == 0) wloss[wave] = lossacc;
    __syncthreads();
    if (tid == 0)
        partials[blockIdx.x] = wloss[0] + wloss[1] + wloss[2] + wloss[3];
}

// ---------------------------------------------------------------------------
// Final reduce: 1024 partials -> meta_loss scalar
// ---------------------------------------------------------------------------
__global__ __launch_bounds__(256) void reduce_kernel(
    const float* __restrict__ partials, float* __restrict__ out)
{
    __shared__ float wsum[4];
    const int tid = threadIdx.x;
    float s = partials[tid] + partials[tid + 256] +
              partials[tid + 512] + partials[tid + 768];
    #pragma unroll
    for (int off = 32; off >= 1; off >>= 1) s += __shfl_xor(s, off);
    if ((tid & 63) == 0) wsum[tid >> 6] = s;
    __syncthreads();
    if (tid == 0) {
        const float inv = 1.0f / ((float)T_TASKS * Q_QRY * D_EMB);
        out[0] = (wsum[0] + wsum[1] + wsum[2] + wsum[3]) * inv;
    }
}

extern "C" void kernel_launch(void* const* d_in, const int* in_sizes, int n_in,
                              void* d_out, int out_size, void* d_ws, size_t ws_size,
                              hipStream_t stream)
{
    const float* support_x = (const float*)d_in[0];
    const int*   support_ids = (const int*)d_in[1];
    const float* query_x  = (const float*)d_in[2];
    const float* query_y  = (const float*)d_in[3];
    const float* W1 = (const float*)d_in[4];
    const float* b1 = (const float*)d_in[5];
    const float* W2 = (const float*)d_in[6];
    const float* b2 = (const float*)d_in[7];

    float* ws = (float*)d_ws;
    float* se      = ws;                                   // 16*2048*128
    float* qe      = se + (long)T_TASKS * S_SUP * D_EMB;   // 16*2048*128
    float* protos  = qe + (long)T_TASKS * Q_QRY * D_EMB;   // 16*64*128
    float* partials = protos + (long)T_TASKS * N_WAY * D_EMB; // 1024

    const int rows_s = T_TASKS * S_SUP;   // 32768
    const int rows_q = T_TASKS * Q_QRY;   // 32768

    embed_kernel<<<rows_s / 16, 256, 0, stream>>>(support_x, W1, b1, W2, b2, se);
    embed_kernel<<<rows_q / 16, 256, 0, stream>>>(query_x,  W1, b1, W2, b2, qe);
    proto_kernel<<<T_TASKS * N_WAY, 128, 0, stream>>>(se, support_ids, protos);
    query_kernel<<<T_TASKS * (Q_QRY / QPB), 256, 0, stream>>>(qe, query_y, protos, partials);
    reduce_kernel<<<1, 256, 0, stream>>>(partials, (float*)d_out);
}

// Round 2
// 256.269 us; speedup vs baseline: 2.2964x; 2.2964x over previous
//
#include <hip/hip_runtime.h>
#include <hip/hip_bf16.h>

#define T_TASKS 16
#define S_SUP   2048
#define Q_QRY   2048
#define D_IN    256
#define H_HID   512
#define D_EMB   128
#define N_WAY   64
#define BM      32

typedef unsigned short ushortT;
typedef unsigned int uintT;
using bf16x8 = __attribute__((ext_vector_type(8))) short;
using f32x4  = __attribute__((ext_vector_type(4))) float;

__device__ __forceinline__ ushortT f2b(float f) {
    uintT u = __builtin_bit_cast(uintT, f);
    uintT r = u + 0x7FFFu + ((u >> 16) & 1u);   // round-to-nearest-even
    return (ushortT)(r >> 16);
}

// ---------------------------------------------------------------------------
// Convert weights fp32 -> bf16, transposed to [N][K] so MFMA B-fragments are
// contiguous 16B loads.
// ---------------------------------------------------------------------------
__global__ __launch_bounds__(256) void convert_weights(
    const float* __restrict__ W1, const float* __restrict__ W2,
    ushortT* __restrict__ W1t, ushortT* __restrict__ W2t)
{
    int i = blockIdx.x * 256 + threadIdx.x;
    if (i < D_IN * H_HID) {              // W1 [256][512] -> W1t [512][256]
        int k = i >> 9, n = i & 511;
        W1t[n * D_IN + k] = f2b(W1[i]);
    }
    if (i < H_HID * D_EMB) {             // W2 [512][128] -> W2t [128][512]
        int k = i >> 7, n = i & 127;
        W2t[n * H_HID + k] = f2b(W2[i]);
    }
}

// ---------------------------------------------------------------------------
// Fused MFMA embed: out[row] = relu(x @ W1 + b1) @ W2 + b2
// 256 threads (4 waves) per block, BM=32 rows per block.
// A-frag (16x16x32): lane l holds row=l&15, k=(l>>4)*8+j
// B-frag:            lane l holds col=l&15, k=(l>>4)*8+j  (W*t is [N][K])
// C/D:               lane l reg r -> row=(l>>4)*4+r, col=l&15   [m89]
// ---------------------------------------------------------------------------
__global__ __launch_bounds__(256) void embed_mfma(
    const float* __restrict__ x, const ushortT* __restrict__ W1t,
    const float* __restrict__ b1, const ushortT* __restrict__ W2t,
    const float* __restrict__ b2, float* __restrict__ out)
{
    __shared__ ushortT xs[BM * D_IN];   // 16 KiB, XOR-swizzled
    __shared__ ushortT hs[BM * H_HID];  // 32 KiB, XOR-swizzled

    const int tid  = threadIdx.x;
    const int wave = tid >> 6;
    const int lane = tid & 63;
    const int lr   = lane & 15;   // A-row / B-col / C-col
    const int lg   = lane >> 4;   // k-group
    const long rowbase = (long)blockIdx.x * BM;

    // ---- stage X tile as bf16 into swizzled LDS -------------------------
    #pragma unroll
    for (int i = 0; i < 4; ++i) {
        int ci   = tid + 256 * i;        // chunk of 8 elems
        int row  = ci >> 5;              // 32 chunks per row
        int col8 = (ci & 31) << 3;
        const float4* p = (const float4*)(x + (rowbase + row) * D_IN + col8);
        float4 a = p[0], b = p[1];
        uint4 v;
        v.x = (uintT)f2b(a.x) | ((uintT)f2b(a.y) << 16);
        v.y = (uintT)f2b(a.z) | ((uintT)f2b(a.w) << 16);
        v.z = (uintT)f2b(b.x) | ((uintT)f2b(b.y) << 16);
        v.w = (uintT)f2b(b.z) | ((uintT)f2b(b.w) << 16);
        int idx = (row << 8) + col8;
        idx ^= (row & 7) << 3;           // 16B-granular XOR swizzle
        *(uint4*)&xs[idx] = v;
    }
    __syncthreads();

    // ---- GEMM1: [32 x 256] @ W1t^T -> relu -> hs [32 x 512] -------------
    {
        f32x4 acc[2][8];
        #pragma unroll
        for (int n = 0; n < 8; ++n) {
            float bv = b1[wave * 128 + n * 16 + lr];
            f32x4 b4 = {bv, bv, bv, bv};
            acc[0][n] = b4; acc[1][n] = b4;
        }
        const ushortT* w1base = W1t + (wave * 128 + lr) * D_IN + lg * 8;
        for (int kk = 0; kk < 8; ++kk) {
            bf16x8 afrag[2];
            #pragma unroll
            for (int m = 0; m < 2; ++m) {
                int row = m * 16 + lr;
                int idx = (row << 8) + kk * 32 + lg * 8;
                idx ^= (row & 7) << 3;
                afrag[m] = *(const bf16x8*)&xs[idx];
            }
            #pragma unroll
            for (int n = 0; n < 8; ++n) {
                bf16x8 bfrag = *(const bf16x8*)(w1base + (n * 16) * D_IN + kk * 32);
                acc[0][n] = __builtin_amdgcn_mfma_f32_16x16x32_bf16(afrag[0], bfrag, acc[0][n], 0, 0, 0);
                acc[1][n] = __builtin_amdgcn_mfma_f32_16x16x32_bf16(afrag[1], bfrag, acc[1][n], 0, 0, 0);
            }
        }
        // relu -> bf16 -> swizzled hs
        #pragma unroll
        for (int m = 0; m < 2; ++m) {
            #pragma unroll
            for (int n = 0; n < 8; ++n) {
                int col = wave * 128 + n * 16 + lr;
                #pragma unroll
                for (int r = 0; r < 4; ++r) {
                    int row = m * 16 + lg * 4 + r;
                    float v = fmaxf(acc[m][n][r], 0.0f);
                    int idx = row * H_HID + col;
                    idx ^= (row & 7) << 3;
                    hs[idx] = f2b(v);
                }
            }
        }
    }
    __syncthreads();

    // ---- GEMM2: [32 x 512] @ W2t^T -> out [32 x 128] --------------------
    {
        f32x4 acc2[2][2];
        #pragma unroll
        for (int n = 0; n < 2; ++n) {
            float bv = b2[wave * 32 + n * 16 + lr];
            f32x4 b4 = {bv, bv, bv, bv};
            acc2[0][n] = b4; acc2[1][n] = b4;
        }
        const ushortT* w2base = W2t + (wave * 32 + lr) * H_HID + lg * 8;
        for (int kk = 0; kk < 16; ++kk) {
            bf16x8 afrag[2];
            #pragma unroll
            for (int m = 0; m < 2; ++m) {
                int row = m * 16 + lr;
                int idx = row * H_HID + kk * 32 + lg * 8;
                idx ^= (row & 7) << 3;
                afrag[m] = *(const bf16x8*)&hs[idx];
            }
            #pragma unroll
            for (int n = 0; n < 2; ++n) {
                bf16x8 bfrag = *(const bf16x8*)(w2base + (n * 16) * H_HID + kk * 32);
                acc2[0][n] = __builtin_amdgcn_mfma_f32_16x16x32_bf16(afrag[0], bfrag, acc2[0][n], 0, 0, 0);
                acc2[1][n] = __builtin_amdgcn_mfma_f32_16x16x32_bf16(afrag[1], bfrag, acc2[1][n], 0, 0, 0);
            }
        }
        #pragma unroll
        for (int m = 0; m < 2; ++m)
            #pragma unroll
            for (int n = 0; n < 2; ++n)
                #pragma unroll
                for (int r = 0; r < 4; ++r) {
                    long row = rowbase + m * 16 + lg * 4 + r;
                    int  col = wave * 32 + n * 16 + lr;
                    out[row * D_EMB + col] = acc2[m][n][r];
                }
    }
}

// ---------------------------------------------------------------------------
// Prototypes: block (t,c) gathers mean of se rows whose id == c.
// ---------------------------------------------------------------------------
__global__ __launch_bounds__(128) void proto_kernel(
    const float* __restrict__ se, const int* __restrict__ ids,
    float* __restrict__ protos)
{
    const int t = blockIdx.x >> 6;
    const int c = blockIdx.x & 63;
    const int d = threadIdx.x;

    const int* idrow = ids + t * S_SUP;
    const float* serow = se + (long)t * S_SUP * D_EMB;

    float acc = 0.0f;
    int cnt = 0;
    for (int s = 0; s < S_SUP; ++s) {
        if (idrow[s] == c) {
            acc += serow[(long)s * D_EMB + d];
            cnt++;
        }
    }
    float denom = (float)(cnt > 0 ? cnt : 1);
    protos[((long)t * N_WAY + c) * D_EMB + d] = acc / denom;
}

// ---------------------------------------------------------------------------
// Query: dist -> softmax -> pred -> squared error.
// ---------------------------------------------------------------------------
#define QPB 32

__global__ __launch_bounds__(256) void query_kernel(
    const float* __restrict__ qe, const float* __restrict__ qy,
    const float* __restrict__ protos, float* __restrict__ partials)
{
    __shared__ float ps[N_WAY][D_EMB + 1];
    __shared__ float qes[4][D_EMB];
    __shared__ float probs[4][N_WAY];
    __shared__ float wloss[4];

    const int tid  = threadIdx.x;
    const int t    = blockIdx.x >> 6;
    const int q0   = (blockIdx.x & 63) * QPB;
    const int wave = tid >> 6;
    const int lane = tid & 63;

    {
        const float* pt = protos + (long)t * N_WAY * D_EMB;
        #pragma unroll
        for (int i = 0; i < 32; ++i) {
            int idx = tid + 256 * i;
            ps[idx >> 7][idx & 127] = pt[idx];
        }
    }
    __syncthreads();

    float lossacc = 0.0f;

    for (int qi = wave; qi < QPB; qi += 4) {
        const long q = q0 + qi;
        const float* qrow = qe + ((long)t * Q_QRY + q) * D_EMB;

        qes[wave][lane]      = qrow[lane];
        qes[wave][lane + 64] = qrow[lane + 64];
        __syncthreads();

        float s = 0.0f;
        #pragma unroll 16
        for (int d = 0; d < D_EMB; ++d) {
            float diff = qes[wave][d] - ps[lane][d];
            s += diff * diff;
        }
        float logit = -sqrtf(s);

        float m = logit;
        #pragma unroll
        for (int off = 32; off >= 1; off >>= 1) m = fmaxf(m, __shfl_xor(m, off));
        float e = __expf(logit - m);
        float sum = e;
        #pragma unroll
        for (int off = 32; off >= 1; off >>= 1) sum += __shfl_xor(sum, off);
        probs[wave][lane] = e / sum;
        __syncthreads();

        float pr0 = 0.0f, pr1 = 0.0f;
        #pragma unroll 16
        for (int c = 0; c < N_WAY; ++c) {
            float p = probs[wave][c];
            pr0 += p * ps[c][lane];
            pr1 += p * ps[c][lane + 64];
        }
        const float* yrow = qy + ((long)t * Q_QRY + q) * D_EMB;
        float d0 = pr0 - yrow[lane];
        float d1 = pr1 - yrow[lane + 64];
        lossacc += d0 * d0 + d1 * d1;
        __syncthreads();
    }

    #pragma unroll
    for (int off = 32; off >= 1; off >>= 1) lossacc += __shfl_xor(lossacc, off);
    if (lane == 0) wloss[wave] = lossacc;
    __syncthreads();
    if (tid == 0)
        partials[blockIdx.x] = wloss[0] + wloss[1] + wloss[2] + wloss[3];
}

__global__ __launch_bounds__(256) void reduce_kernel(
    const float* __restrict__ partials, float* __restrict__ out)
{
    __shared__ float wsum[4];
    const int tid = threadIdx.x;
    float s = partials[tid] + partials[tid + 256] +
              partials[tid + 512] + partials[tid + 768];
    #pragma unroll
    for (int off = 32; off >= 1; off >>= 1) s += __shfl_xor(s, off);
    if ((tid & 63) == 0) wsum[tid >> 6] = s;
    __syncthreads();
    if (tid == 0) {
        const float inv = 1.0f / ((float)T_TASKS * Q_QRY * D_EMB);
        out[0] = (wsum[0] + wsum[1] + wsum[2] + wsum[3]) * inv;
    }
}

extern "C" void kernel_launch(void* const* d_in, const int* in_sizes, int n_in,
                              void* d_out, int out_size, void* d_ws, size_t ws_size,
                              hipStream_t stream)
{
    const float* support_x = (const float*)d_in[0];
    const int*   support_ids = (const int*)d_in[1];
    const float* query_x  = (const float*)d_in[2];
    const float* query_y  = (const float*)d_in[3];
    const float* W1 = (const float*)d_in[4];
    const float* b1 = (const float*)d_in[5];
    const float* W2 = (const float*)d_in[6];
    const float* b2 = (const float*)d_in[7];

    float* ws = (float*)d_ws;
    float* se       = ws;                                        // 16*2048*128
    float* qe       = se + (long)T_TASKS * S_SUP * D_EMB;        // 16*2048*128
    float* protos   = qe + (long)T_TASKS * Q_QRY * D_EMB;        // 16*64*128
    float* partials = protos + (long)T_TASKS * N_WAY * D_EMB;    // 1024
    ushortT* W1t    = (ushortT*)(partials + 1024);               // 512*256
    ushortT* W2t    = W1t + H_HID * D_IN;                        // 128*512

    const int rows_s = T_TASKS * S_SUP;   // 32768
    const int rows_q = T_TASKS * Q_QRY;   // 32768

    convert_weights<<<512, 256, 0, stream>>>(W1, W2, W1t, W2t);
    embed_mfma<<<rows_s / BM, 256, 0, stream>>>(support_x, W1t, b1, W2t, b2, se);
    embed_mfma<<<rows_q / BM, 256, 0, stream>>>(query_x,  W1t, b1, W2t, b2, qe);
    proto_kernel<<<T_TASKS * N_WAY, 128, 0, stream>>>(se, support_ids, protos);
    query_kernel<<<T_TASKS * (Q_QRY / QPB), 256, 0, stream>>>(qe, query_y, protos, partials);
    reduce_kernel<<<1, 256, 0, stream>>>(partials, (float*)d_out);
}

// Round 3
// 181.607 us; speedup vs baseline: 3.2405x; 1.4111x over previous
//
#include <hip/hip_runtime.h>
#include <hip/hip_bf16.h>

#define T_TASKS 16
#define S_SUP   2048
#define Q_QRY   2048
#define D_IN    256
#define H_HID   512
#define D_EMB   128
#define N_WAY   64
#define BM      32
#define NCHUNK  16
#define CHUNK   128   // S_SUP / NCHUNK

typedef unsigned short ushortT;
typedef unsigned int uintT;
using bf16x8 = __attribute__((ext_vector_type(8))) short;
using f32x4  = __attribute__((ext_vector_type(4))) float;

__device__ __forceinline__ ushortT f2b(float f) {
    uintT u = __builtin_bit_cast(uintT, f);
    uintT r = u + 0x7FFFu + ((u >> 16) & 1u);   // round-to-nearest-even
    return (ushortT)(r >> 16);
}

// ---------------------------------------------------------------------------
// Convert weights fp32 -> bf16, transposed to [N][K].
// ---------------------------------------------------------------------------
__global__ __launch_bounds__(256) void convert_weights(
    const float* __restrict__ W1, const float* __restrict__ W2,
    ushortT* __restrict__ W1t, ushortT* __restrict__ W2t)
{
    int i = blockIdx.x * 256 + threadIdx.x;
    if (i < D_IN * H_HID) {              // W1 [256][512] -> W1t [512][256]
        int k = i >> 9, n = i & 511;
        W1t[n * D_IN + k] = f2b(W1[i]);
    }
    if (i < H_HID * D_EMB) {             // W2 [512][128] -> W2t [128][512]
        int k = i >> 7, n = i & 127;
        W2t[n * H_HID + k] = f2b(W2[i]);
    }
}

// ---------------------------------------------------------------------------
// Fused MFMA embed: out[row] = relu(x @ W1 + b1) @ W2 + b2
// ---------------------------------------------------------------------------
__global__ __launch_bounds__(256) void embed_mfma(
    const float* __restrict__ x, const ushortT* __restrict__ W1t,
    const float* __restrict__ b1, const ushortT* __restrict__ W2t,
    const float* __restrict__ b2, float* __restrict__ out)
{
    __shared__ ushortT xs[BM * D_IN];   // 16 KiB, XOR-swizzled
    __shared__ ushortT hs[BM * H_HID];  // 32 KiB, XOR-swizzled

    const int tid  = threadIdx.x;
    const int wave = tid >> 6;
    const int lane = tid & 63;
    const int lr   = lane & 15;   // A-row / B-col / C-col
    const int lg   = lane >> 4;   // k-group
    const long rowbase = (long)blockIdx.x * BM;

    // ---- stage X tile as bf16 into swizzled LDS -------------------------
    #pragma unroll
    for (int i = 0; i < 4; ++i) {
        int ci   = tid + 256 * i;        // chunk of 8 elems
        int row  = ci >> 5;              // 32 chunks per row
        int col8 = (ci & 31) << 3;
        const float4* p = (const float4*)(x + (rowbase + row) * D_IN + col8);
        float4 a = p[0], b = p[1];
        uint4 v;
        v.x = (uintT)f2b(a.x) | ((uintT)f2b(a.y) << 16);
        v.y = (uintT)f2b(a.z) | ((uintT)f2b(a.w) << 16);
        v.z = (uintT)f2b(b.x) | ((uintT)f2b(b.y) << 16);
        v.w = (uintT)f2b(b.z) | ((uintT)f2b(b.w) << 16);
        int idx = (row << 8) + col8;
        idx ^= (row & 7) << 3;           // 16B-granular XOR swizzle
        *(uint4*)&xs[idx] = v;
    }
    __syncthreads();

    // ---- GEMM1: [32 x 256] @ W1t^T -> relu -> hs [32 x 512] -------------
    {
        f32x4 acc[2][8];
        #pragma unroll
        for (int n = 0; n < 8; ++n) {
            float bv = b1[wave * 128 + n * 16 + lr];
            f32x4 b4 = {bv, bv, bv, bv};
            acc[0][n] = b4; acc[1][n] = b4;
        }
        const ushortT* w1base = W1t + (wave * 128 + lr) * D_IN + lg * 8;
        for (int kk = 0; kk < 8; ++kk) {
            bf16x8 afrag[2];
            #pragma unroll
            for (int m = 0; m < 2; ++m) {
                int row = m * 16 + lr;
                int idx = (row << 8) + kk * 32 + lg * 8;
                idx ^= (row & 7) << 3;
                afrag[m] = *(const bf16x8*)&xs[idx];
            }
            #pragma unroll
            for (int n = 0; n < 8; ++n) {
                bf16x8 bfrag = *(const bf16x8*)(w1base + (n * 16) * D_IN + kk * 32);
                acc[0][n] = __builtin_amdgcn_mfma_f32_16x16x32_bf16(afrag[0], bfrag, acc[0][n], 0, 0, 0);
                acc[1][n] = __builtin_amdgcn_mfma_f32_16x16x32_bf16(afrag[1], bfrag, acc[1][n], 0, 0, 0);
            }
        }
        #pragma unroll
        for (int m = 0; m < 2; ++m) {
            #pragma unroll
            for (int n = 0; n < 8; ++n) {
                int col = wave * 128 + n * 16 + lr;
                #pragma unroll
                for (int r = 0; r < 4; ++r) {
                    int row = m * 16 + lg * 4 + r;
                    float v = fmaxf(acc[m][n][r], 0.0f);
                    int idx = row * H_HID + col;
                    idx ^= (row & 7) << 3;
                    hs[idx] = f2b(v);
                }
            }
        }
    }
    __syncthreads();

    // ---- GEMM2: [32 x 512] @ W2t^T -> out [32 x 128] --------------------
    {
        f32x4 acc2[2][2];
        #pragma unroll
        for (int n = 0; n < 2; ++n) {
            float bv = b2[wave * 32 + n * 16 + lr];
            f32x4 b4 = {bv, bv, bv, bv};
            acc2[0][n] = b4; acc2[1][n] = b4;
        }
        const ushortT* w2base = W2t + (wave * 32 + lr) * H_HID + lg * 8;
        for (int kk = 0; kk < 16; ++kk) {
            bf16x8 afrag[2];
            #pragma unroll
            for (int m = 0; m < 2; ++m) {
                int row = m * 16 + lr;
                int idx = row * H_HID + kk * 32 + lg * 8;
                idx ^= (row & 7) << 3;
                afrag[m] = *(const bf16x8*)&hs[idx];
            }
            #pragma unroll
            for (int n = 0; n < 2; ++n) {
                bf16x8 bfrag = *(const bf16x8*)(w2base + (n * 16) * H_HID + kk * 32);
                acc2[0][n] = __builtin_amdgcn_mfma_f32_16x16x32_bf16(afrag[0], bfrag, acc2[0][n], 0, 0, 0);
                acc2[1][n] = __builtin_amdgcn_mfma_f32_16x16x32_bf16(afrag[1], bfrag, acc2[1][n], 0, 0, 0);
            }
        }
        #pragma unroll
        for (int m = 0; m < 2; ++m)
            #pragma unroll
            for (int n = 0; n < 2; ++n)
                #pragma unroll
                for (int r = 0; r < 4; ++r) {
                    long row = rowbase + m * 16 + lg * 4 + r;
                    int  col = wave * 32 + n * 16 + lr;
                    out[row * D_EMB + col] = acc2[m][n][r];
                }
    }
}

// ---------------------------------------------------------------------------
// Proto phase 1: block = (t, chunk of 128 rows). 256 threads, two independent
// 64-row accumulation streams in LDS. Deterministic (fixed order, no atomics).
// ---------------------------------------------------------------------------
__global__ __launch_bounds__(256) void proto_partial(
    const float* __restrict__ se, const int* __restrict__ ids,
    float* __restrict__ psum, int* __restrict__ pcnt)
{
    __shared__ float acc[2][N_WAY][D_EMB];  // 64 KiB
    __shared__ int idbuf[CHUNK];

    const int tid  = threadIdx.x;
    const int t    = blockIdx.x >> 4;
    const int ch   = blockIdx.x & 15;
    const int d    = tid & 127;
    const int half = tid >> 7;

    // init accumulators (2*64*128 = 16384 floats, 64 per thread)
    #pragma unroll
    for (int i = 0; i < 64; ++i)
        ((float*)acc)[tid + 256 * i] = 0.0f;
    if (tid < CHUNK) idbuf[tid] = ids[t * S_SUP + ch * CHUNK + tid];
    __syncthreads();

    const float* sb = se + ((long)t * S_SUP + ch * CHUNK) * D_EMB;
    #pragma unroll 4
    for (int s = 0; s < 64; ++s) {
        int row = half * 64 + s;
        int c = idbuf[row];
        acc[half][c][d] += sb[(long)row * D_EMB + d];
    }
    __syncthreads();

    // write out 64x128 partial sums (combine halves): 32 per thread
    float* pb = psum + (long)blockIdx.x * N_WAY * D_EMB;
    #pragma unroll
    for (int i = 0; i < 32; ++i) {
        int idx = tid + 256 * i;
        pb[idx] = acc[0][idx >> 7][idx & 127] + acc[1][idx >> 7][idx & 127];
    }
    // counts for this chunk
    if (tid < N_WAY) {
        int cnt = 0;
        #pragma unroll 8
        for (int s = 0; s < CHUNK; ++s) cnt += (idbuf[s] == tid);
        pcnt[blockIdx.x * N_WAY + tid] = cnt;
    }
}

// ---------------------------------------------------------------------------
// Proto phase 2: one thread per (t,c,d) reduces the 16 chunk partials.
// ---------------------------------------------------------------------------
__global__ __launch_bounds__(256) void proto_reduce(
    const float* __restrict__ psum, const int* __restrict__ pcnt,
    float* __restrict__ protos)
{
    int idx = blockIdx.x * 256 + threadIdx.x;     // (t,c,d) flat, 131072 total
    int t = idx >> 13;
    int cd = idx & 8191;
    int c = cd >> 7;

    float s = 0.0f;
    int cnt = 0;
    #pragma unroll
    for (int ch = 0; ch < NCHUNK; ++ch) {
        s   += psum[((long)(t * NCHUNK + ch)) * N_WAY * D_EMB + cd];
        cnt += pcnt[(t * NCHUNK + ch) * N_WAY + c];
    }
    protos[idx] = s / (float)(cnt > 0 ? cnt : 1);
}

// ---------------------------------------------------------------------------
// Query: dist -> softmax -> pred -> squared error.
// ---------------------------------------------------------------------------
#define QPB 32

__global__ __launch_bounds__(256) void query_kernel(
    const float* __restrict__ qe, const float* __restrict__ qy,
    const float* __restrict__ protos, float* __restrict__ partials)
{
    __shared__ float ps[N_WAY][D_EMB + 1];
    __shared__ float qes[4][D_EMB];
    __shared__ float probs[4][N_WAY];
    __shared__ float wloss[4];

    const int tid  = threadIdx.x;
    const int t    = blockIdx.x >> 6;
    const int q0   = (blockIdx.x & 63) * QPB;
    const int wave = tid >> 6;
    const int lane = tid & 63;

    {
        const float* pt = protos + (long)t * N_WAY * D_EMB;
        #pragma unroll
        for (int i = 0; i < 32; ++i) {
            int idx = tid + 256 * i;
            ps[idx >> 7][idx & 127] = pt[idx];
        }
    }
    __syncthreads();

    float lossacc = 0.0f;

    for (int qi = wave; qi < QPB; qi += 4) {
        const long q = q0 + qi;
        const float* qrow = qe + ((long)t * Q_QRY + q) * D_EMB;

        qes[wave][lane]      = qrow[lane];
        qes[wave][lane + 64] = qrow[lane + 64];
        __syncthreads();

        float s = 0.0f;
        #pragma unroll 16
        for (int d = 0; d < D_EMB; ++d) {
            float diff = qes[wave][d] - ps[lane][d];
            s += diff * diff;
        }
        float logit = -sqrtf(s);

        float m = logit;
        #pragma unroll
        for (int off = 32; off >= 1; off >>= 1) m = fmaxf(m, __shfl_xor(m, off));
        float e = __expf(logit - m);
        float sum = e;
        #pragma unroll
        for (int off = 32; off >= 1; off >>= 1) sum += __shfl_xor(sum, off);
        probs[wave][lane] = e / sum;
        __syncthreads();

        float pr0 = 0.0f, pr1 = 0.0f;
        #pragma unroll 16
        for (int c = 0; c < N_WAY; ++c) {
            float p = probs[wave][c];
            pr0 += p * ps[c][lane];
            pr1 += p * ps[c][lane + 64];
        }
        const float* yrow = qy + ((long)t * Q_QRY + q) * D_EMB;
        float d0 = pr0 - yrow[lane];
        float d1 = pr1 - yrow[lane + 64];
        lossacc += d0 * d0 + d1 * d1;
        __syncthreads();
    }

    #pragma unroll
    for (int off = 32; off >= 1; off >>= 1) lossacc += __shfl_xor(lossacc, off);
    if (lane == 0) wloss[wave] = lossacc;
    __syncthreads();
    if (tid == 0)
        partials[blockIdx.x] = wloss[0] + wloss[1] + wloss[2] + wloss[3];
}

__global__ __launch_bounds__(256) void reduce_kernel(
    const float* __restrict__ partials, float* __restrict__ out)
{
    __shared__ float wsum[4];
    const int tid = threadIdx.x;
    float s = partials[tid] + partials[tid + 256] +
              partials[tid + 512] + partials[tid + 768];
    #pragma unroll
    for (int off = 32; off >= 1; off >>= 1) s += __shfl_xor(s, off);
    if ((tid & 63) == 0) wsum[tid >> 6] = s;
    __syncthreads();
    if (tid == 0) {
        const float inv = 1.0f / ((float)T_TASKS * Q_QRY * D_EMB);
        out[0] = (wsum[0] + wsum[1] + wsum[2] + wsum[3]) * inv;
    }
}

extern "C" void kernel_launch(void* const* d_in, const int* in_sizes, int n_in,
                              void* d_out, int out_size, void* d_ws, size_t ws_size,
                              hipStream_t stream)
{
    const float* support_x = (const float*)d_in[0];
    const int*   support_ids = (const int*)d_in[1];
    const float* query_x  = (const float*)d_in[2];
    const float* query_y  = (const float*)d_in[3];
    const float* W1 = (const float*)d_in[4];
    const float* b1 = (const float*)d_in[5];
    const float* W2 = (const float*)d_in[6];
    const float* b2 = (const float*)d_in[7];

    float* ws = (float*)d_ws;
    float* se       = ws;                                        // 16*2048*128 = 4.19M
    float* qe       = se + (long)T_TASKS * S_SUP * D_EMB;        // 4.19M
    float* protos   = qe + (long)T_TASKS * Q_QRY * D_EMB;        // 131072
    float* partials = protos + (long)T_TASKS * N_WAY * D_EMB;    // 1024
    ushortT* W1t    = (ushortT*)(partials + 1024);               // 512*256 bf16
    ushortT* W2t    = W1t + H_HID * D_IN;                        // 128*512 bf16
    float* psum     = (float*)(W2t + D_EMB * H_HID);             // 256*64*128 = 2.10M
    int*   pcnt     = (int*)(psum + (long)T_TASKS * NCHUNK * N_WAY * D_EMB); // 16384

    const int rows_s = T_TASKS * S_SUP;   // 32768
    const int rows_q = T_TASKS * Q_QRY;   // 32768

    convert_weights<<<512, 256, 0, stream>>>(W1, W2, W1t, W2t);
    embed_mfma<<<rows_s / BM, 256, 0, stream>>>(support_x, W1t, b1, W2t, b2, se);
    embed_mfma<<<rows_q / BM, 256, 0, stream>>>(query_x,  W1t, b1, W2t, b2, qe);
    proto_partial<<<T_TASKS * NCHUNK, 256, 0, stream>>>(se, support_ids, psum, pcnt);
    proto_reduce<<<512, 256, 0, stream>>>(psum, pcnt, protos);
    query_kernel<<<T_TASKS * (Q_QRY / QPB), 256, 0, stream>>>(qe, query_y, protos, partials);
    reduce_kernel<<<1, 256, 0, stream>>>(partials, (float*)d_out);
}

// Round 4
// 134.760 us; speedup vs baseline: 4.3669x; 1.3476x over previous
//
#include <hip/hip_runtime.h>
#include <hip/hip_bf16.h>

#define T_TASKS 16
#define S_SUP   2048
#define Q_QRY   2048
#define D_IN    256
#define H_HID   512
#define D_EMB   128
#define N_WAY   64
#define BM      32
#define NCHUNK  16
#define CHUNK   128   // S_SUP / NCHUNK
#define QB      64    // queries per block in query_mfma

typedef unsigned short ushortT;
typedef unsigned int uintT;
using bf16x8 = __attribute__((ext_vector_type(8))) short;
using f32x4  = __attribute__((ext_vector_type(4))) float;

__device__ __forceinline__ ushortT f2b(float f) {
    uintT u = __builtin_bit_cast(uintT, f);
    uintT r = u + 0x7FFFu + ((u >> 16) & 1u);   // round-to-nearest-even
    return (ushortT)(r >> 16);
}
__device__ __forceinline__ float b2f(ushortT h) {
    return __builtin_bit_cast(float, (uintT)h << 16);
}

// ---------------------------------------------------------------------------
// Convert weights fp32 -> bf16, transposed to [N][K].
// ---------------------------------------------------------------------------
__global__ __launch_bounds__(256) void convert_weights(
    const float* __restrict__ W1, const float* __restrict__ W2,
    ushortT* __restrict__ W1t, ushortT* __restrict__ W2t)
{
    int i = blockIdx.x * 256 + threadIdx.x;
    if (i < D_IN * H_HID) {              // W1 [256][512] -> W1t [512][256]
        int k = i >> 9, n = i & 511;
        W1t[n * D_IN + k] = f2b(W1[i]);
    }
    if (i < H_HID * D_EMB) {             // W2 [512][128] -> W2t [128][512]
        int k = i >> 7, n = i & 127;
        W2t[n * H_HID + k] = f2b(W2[i]);
    }
}

// ---------------------------------------------------------------------------
// Fused MFMA embed: out[row] = relu(x @ W1 + b1) @ W2 + b2
// ---------------------------------------------------------------------------
__global__ __launch_bounds__(256) void embed_mfma(
    const float* __restrict__ x, const ushortT* __restrict__ W1t,
    const float* __restrict__ b1, const ushortT* __restrict__ W2t,
    const float* __restrict__ b2, float* __restrict__ out)
{
    __shared__ ushortT xs[BM * D_IN];   // 16 KiB, XOR-swizzled
    __shared__ ushortT hs[BM * H_HID];  // 32 KiB, XOR-swizzled

    const int tid  = threadIdx.x;
    const int wave = tid >> 6;
    const int lane = tid & 63;
    const int lr   = lane & 15;   // A-row / B-col / C-col
    const int lg   = lane >> 4;   // k-group
    const long rowbase = (long)blockIdx.x * BM;

    #pragma unroll
    for (int i = 0; i < 4; ++i) {
        int ci   = tid + 256 * i;        // chunk of 8 elems
        int row  = ci >> 5;              // 32 chunks per row
        int col8 = (ci & 31) << 3;
        const float4* p = (const float4*)(x + (rowbase + row) * D_IN + col8);
        float4 a = p[0], b = p[1];
        uint4 v;
        v.x = (uintT)f2b(a.x) | ((uintT)f2b(a.y) << 16);
        v.y = (uintT)f2b(a.z) | ((uintT)f2b(a.w) << 16);
        v.z = (uintT)f2b(b.x) | ((uintT)f2b(b.y) << 16);
        v.w = (uintT)f2b(b.z) | ((uintT)f2b(b.w) << 16);
        int idx = (row << 8) + col8;
        idx ^= (row & 7) << 3;           // 16B-granular XOR swizzle
        *(uint4*)&xs[idx] = v;
    }
    __syncthreads();

    // GEMM1: [32 x 256] @ W1t^T -> relu -> hs [32 x 512]
    {
        f32x4 acc[2][8];
        #pragma unroll
        for (int n = 0; n < 8; ++n) {
            float bv = b1[wave * 128 + n * 16 + lr];
            f32x4 b4 = {bv, bv, bv, bv};
            acc[0][n] = b4; acc[1][n] = b4;
        }
        const ushortT* w1base = W1t + (wave * 128 + lr) * D_IN + lg * 8;
        for (int kk = 0; kk < 8; ++kk) {
            bf16x8 afrag[2];
            #pragma unroll
            for (int m = 0; m < 2; ++m) {
                int row = m * 16 + lr;
                int idx = (row << 8) + kk * 32 + lg * 8;
                idx ^= (row & 7) << 3;
                afrag[m] = *(const bf16x8*)&xs[idx];
            }
            #pragma unroll
            for (int n = 0; n < 8; ++n) {
                bf16x8 bfrag = *(const bf16x8*)(w1base + (n * 16) * D_IN + kk * 32);
                acc[0][n] = __builtin_amdgcn_mfma_f32_16x16x32_bf16(afrag[0], bfrag, acc[0][n], 0, 0, 0);
                acc[1][n] = __builtin_amdgcn_mfma_f32_16x16x32_bf16(afrag[1], bfrag, acc[1][n], 0, 0, 0);
            }
        }
        #pragma unroll
        for (int m = 0; m < 2; ++m) {
            #pragma unroll
            for (int n = 0; n < 8; ++n) {
                int col = wave * 128 + n * 16 + lr;
                #pragma unroll
                for (int r = 0; r < 4; ++r) {
                    int row = m * 16 + lg * 4 + r;
                    float v = fmaxf(acc[m][n][r], 0.0f);
                    int idx = row * H_HID + col;
                    idx ^= (row & 7) << 3;
                    hs[idx] = f2b(v);
                }
            }
        }
    }
    __syncthreads();

    // GEMM2: [32 x 512] @ W2t^T -> out [32 x 128]
    {
        f32x4 acc2[2][2];
        #pragma unroll
        for (int n = 0; n < 2; ++n) {
            float bv = b2[wave * 32 + n * 16 + lr];
            f32x4 b4 = {bv, bv, bv, bv};
            acc2[0][n] = b4; acc2[1][n] = b4;
        }
        const ushortT* w2base = W2t + (wave * 32 + lr) * H_HID + lg * 8;
        for (int kk = 0; kk < 16; ++kk) {
            bf16x8 afrag[2];
            #pragma unroll
            for (int m = 0; m < 2; ++m) {
                int row = m * 16 + lr;
                int idx = row * H_HID + kk * 32 + lg * 8;
                idx ^= (row & 7) << 3;
                afrag[m] = *(const bf16x8*)&hs[idx];
            }
            #pragma unroll
            for (int n = 0; n < 2; ++n) {
                bf16x8 bfrag = *(const bf16x8*)(w2base + (n * 16) * H_HID + kk * 32);
                acc2[0][n] = __builtin_amdgcn_mfma_f32_16x16x32_bf16(afrag[0], bfrag, acc2[0][n], 0, 0, 0);
                acc2[1][n] = __builtin_amdgcn_mfma_f32_16x16x32_bf16(afrag[1], bfrag, acc2[1][n], 0, 0, 0);
            }
        }
        #pragma unroll
        for (int m = 0; m < 2; ++m)
            #pragma unroll
            for (int n = 0; n < 2; ++n)
                #pragma unroll
                for (int r = 0; r < 4; ++r) {
                    long row = rowbase + m * 16 + lg * 4 + r;
                    int  col = wave * 32 + n * 16 + lr;
                    out[row * D_EMB + col] = acc2[m][n][r];
                }
    }
}

// ---------------------------------------------------------------------------
// Proto phase 1: block = (t, chunk of 128 rows), two LDS accumulation streams.
// ---------------------------------------------------------------------------
__global__ __launch_bounds__(256) void proto_partial(
    const float* __restrict__ se, const int* __restrict__ ids,
    float* __restrict__ psum, int* __restrict__ pcnt)
{
    __shared__ float acc[2][N_WAY][D_EMB];  // 64 KiB
    __shared__ int idbuf[CHUNK];

    const int tid  = threadIdx.x;
    const int t    = blockIdx.x >> 4;
    const int ch   = blockIdx.x & 15;
    const int d    = tid & 127;
    const int half = tid >> 7;

    #pragma unroll
    for (int i = 0; i < 64; ++i)
        ((float*)acc)[tid + 256 * i] = 0.0f;
    if (tid < CHUNK) idbuf[tid] = ids[t * S_SUP + ch * CHUNK + tid];
    __syncthreads();

    const float* sb = se + ((long)t * S_SUP + ch * CHUNK) * D_EMB;
    #pragma unroll 4
    for (int s = 0; s < 64; ++s) {
        int row = half * 64 + s;
        int c = idbuf[row];
        acc[half][c][d] += sb[(long)row * D_EMB + d];
    }
    __syncthreads();

    float* pb = psum + (long)blockIdx.x * N_WAY * D_EMB;
    #pragma unroll
    for (int i = 0; i < 32; ++i) {
        int idx = tid + 256 * i;
        pb[idx] = acc[0][idx >> 7][idx & 127] + acc[1][idx >> 7][idx & 127];
    }
    if (tid < N_WAY) {
        int cnt = 0;
        #pragma unroll 8
        for (int s = 0; s < CHUNK; ++s) cnt += (idbuf[s] == tid);
        pcnt[blockIdx.x * N_WAY + tid] = cnt;
    }
}

__global__ __launch_bounds__(256) void proto_reduce(
    const float* __restrict__ psum, const int* __restrict__ pcnt,
    float* __restrict__ protos)
{
    int idx = blockIdx.x * 256 + threadIdx.x;
    int t = idx >> 13;
    int cd = idx & 8191;
    int c = cd >> 7;

    float s = 0.0f;
    int cnt = 0;
    #pragma unroll
    for (int ch = 0; ch < NCHUNK; ++ch) {
        s   += psum[((long)(t * NCHUNK + ch)) * N_WAY * D_EMB + cd];
        cnt += pcnt[(t * NCHUNK + ch) * N_WAY + c];
    }
    protos[idx] = s / (float)(cnt > 0 ? cnt : 1);
}

// ---------------------------------------------------------------------------
// query_mfma: per block (4 waves, 64 queries of one task):
//   qpT[c][q] = protos . qe^T  (MFMA, A=protos row-major, B=qe row-major)
//   dist -> in-register softmax (shfl over lg groups)
//   probs -> per-wave LDS tile -> pred = probs . protos (MFMA, B=psT[d][c])
//   fused squared-error reduction -> partials[block]
// ---------------------------------------------------------------------------
__global__ __launch_bounds__(256) void query_mfma(
    const float* __restrict__ qe, const float* __restrict__ qy,
    const float* __restrict__ protos_g, float* __restrict__ partials)
{
    __shared__ ushortT psA[N_WAY * D_EMB];       // [c][d] swizzled, 16 KiB
    __shared__ ushortT psT[D_EMB * N_WAY];       // [d][c] swizzled, 16 KiB
    __shared__ ushortT probs_s[4][16 * N_WAY];   // per-wave [q][c] swizzled, 8 KiB
    __shared__ float p2s[N_WAY];
    __shared__ float wloss[4];

    const int tid  = threadIdx.x;
    const int wave = tid >> 6;
    const int lane = tid & 63;
    const int lr   = lane & 15;
    const int lg   = lane >> 4;
    const int t    = blockIdx.x >> 5;        // 32 blocks per task
    const int qblk = blockIdx.x & 31;

    const float* pt = protos_g + (long)t * N_WAY * D_EMB;

    // ---- stage psA [c][d] bf16 swizzled + per-chunk sumsq for p2 --------
    float pp[4];
    #pragma unroll
    for (int i = 0; i < 4; ++i) {
        int ci = tid + 256 * i;
        int c = ci >> 4, col8 = (ci & 15) << 3;
        const float4* p = (const float4*)(pt + c * D_EMB + col8);
        float4 a = p[0], b = p[1];
        ushortT h0 = f2b(a.x), h1 = f2b(a.y), h2 = f2b(a.z), h3 = f2b(a.w);
        ushortT h4 = f2b(b.x), h5 = f2b(b.y), h6 = f2b(b.z), h7 = f2b(b.w);
        float ss = b2f(h0)*b2f(h0) + b2f(h1)*b2f(h1) + b2f(h2)*b2f(h2) + b2f(h3)*b2f(h3)
                 + b2f(h4)*b2f(h4) + b2f(h5)*b2f(h5) + b2f(h6)*b2f(h6) + b2f(h7)*b2f(h7);
        pp[i] = ss;
        uint4 v;
        v.x = (uintT)h0 | ((uintT)h1 << 16);
        v.y = (uintT)h2 | ((uintT)h3 << 16);
        v.z = (uintT)h4 | ((uintT)h5 << 16);
        v.w = (uintT)h6 | ((uintT)h7 << 16);
        int idx = c * D_EMB + col8;
        idx ^= (c & 7) << 3;
        *(uint4*)&psA[idx] = v;
    }
    // reduce 16 chunk-partials per row c (threads with same tid>>4, one wave)
    #pragma unroll
    for (int off = 1; off < 16; off <<= 1) {
        #pragma unroll
        for (int i = 0; i < 4; ++i) pp[i] += __shfl_xor(pp[i], off);
    }
    if ((lane & 15) == 0) {
        int a = wave * 4 + (lane >> 4);   // a = c & 15
        #pragma unroll
        for (int i = 0; i < 4; ++i) p2s[a + 16 * i] = pp[i];
    }

    // ---- stage psT [d][c] bf16 swizzled (transposed, coalesced reads) ---
    {
        int d  = wave * 32 + (lane & 31);
        int ch = lane >> 5;
        #pragma unroll
        for (int m = 0; m < 4; ++m) {
            ushortT h[8];
            #pragma unroll
            for (int j = 0; j < 8; ++j)
                h[j] = f2b(pt[(ch * 32 + m * 8 + j) * D_EMB + d]);
            uint4 v;
            v.x = (uintT)h[0] | ((uintT)h[1] << 16);
            v.y = (uintT)h[2] | ((uintT)h[3] << 16);
            v.z = (uintT)h[4] | ((uintT)h[5] << 16);
            v.w = (uintT)h[6] | ((uintT)h[7] << 16);
            int idx = d * N_WAY + ch * 32 + m * 8;
            idx ^= (d & 7) << 3;
            *(uint4*)&psT[idx] = v;
        }
    }
    __syncthreads();

    // ---- load qe rows as B-frags (col q = lr), compute q2 ---------------
    const long qrow = (long)t * Q_QRY + qblk * QB + wave * 16 + lr;
    bf16x8 bq[4];
    float q2 = 0.0f;
    #pragma unroll
    for (int kk = 0; kk < 4; ++kk) {
        const float4* p = (const float4*)(qe + qrow * D_EMB + kk * 32 + lg * 8);
        float4 a = p[0], b = p[1];
        ushortT h0 = f2b(a.x), h1 = f2b(a.y), h2 = f2b(a.z), h3 = f2b(a.w);
        ushortT h4 = f2b(b.x), h5 = f2b(b.y), h6 = f2b(b.z), h7 = f2b(b.w);
        q2 += b2f(h0)*b2f(h0) + b2f(h1)*b2f(h1) + b2f(h2)*b2f(h2) + b2f(h3)*b2f(h3)
            + b2f(h4)*b2f(h4) + b2f(h5)*b2f(h5) + b2f(h6)*b2f(h6) + b2f(h7)*b2f(h7);
        uintT w0 = (uintT)h0 | ((uintT)h1 << 16);
        uintT w1 = (uintT)h2 | ((uintT)h3 << 16);
        uintT w2 = (uintT)h4 | ((uintT)h5 << 16);
        uintT w3 = (uintT)h6 | ((uintT)h7 << 16);
        uint4 u = {w0, w1, w2, w3};
        bq[kk] = __builtin_bit_cast(bf16x8, u);
    }
    q2 += __shfl_xor(q2, 16);
    q2 += __shfl_xor(q2, 32);

    // ---- qpT = protos . qe^T : acc[mt][r] = qp[c = mt*16+lg*4+r][q = lr]
    f32x4 acc[4];
    #pragma unroll
    for (int mt = 0; mt < 4; ++mt) { f32x4 z = {0,0,0,0}; acc[mt] = z; }
    #pragma unroll
    for (int kk = 0; kk < 4; ++kk) {
        #pragma unroll
        for (int mt = 0; mt < 4; ++mt) {
            int c = mt * 16 + lr;
            int idx = (c * D_EMB + kk * 32 + lg * 8) ^ ((c & 7) << 3);
            bf16x8 af = *(const bf16x8*)&psA[idx];
            acc[mt] = __builtin_amdgcn_mfma_f32_16x16x32_bf16(af, bq[kk], acc[mt], 0, 0, 0);
        }
    }

    // ---- dist -> in-register softmax over 64 classes --------------------
    float ev[4][4];
    float mx = -1e30f;
    #pragma unroll
    for (int mt = 0; mt < 4; ++mt) {
        #pragma unroll
        for (int r = 0; r < 4; ++r) {
            int c = mt * 16 + lg * 4 + r;
            float d2 = q2 + p2s[c] - 2.0f * acc[mt][r];
            float v = -sqrtf(fmaxf(d2, 0.0f));
            ev[mt][r] = v;
            mx = fmaxf(mx, v);
        }
    }
    mx = fmaxf(mx, __shfl_xor(mx, 16));
    mx = fmaxf(mx, __shfl_xor(mx, 32));
    float sum = 0.0f;
    #pragma unroll
    for (int mt = 0; mt < 4; ++mt)
        #pragma unroll
        for (int r = 0; r < 4; ++r) {
            float e = __expf(ev[mt][r] - mx);
            ev[mt][r] = e;
            sum += e;
        }
    sum += __shfl_xor(sum, 16);
    sum += __shfl_xor(sum, 32);
    float inv = 1.0f / sum;

    // ---- probs -> per-wave LDS tile [q][c] bf16 swizzled ----------------
    #pragma unroll
    for (int mt = 0; mt < 4; ++mt) {
        uintT lo = (uintT)f2b(ev[mt][0] * inv) | ((uintT)f2b(ev[mt][1] * inv) << 16);
        uintT hi = (uintT)f2b(ev[mt][2] * inv) | ((uintT)f2b(ev[mt][3] * inv) << 16);
        int idx = lr * N_WAY + ((mt * 16 + lg * 4) ^ ((lr & 7) << 3));
        uint2 v = {lo, hi};
        *(uint2*)&probs_s[wave][idx] = v;
    }

    // ---- pred = probs . protos : acc2[nt][r] = pred[q=lg*4+r][d=nt*16+lr]
    f32x4 acc2[8];
    #pragma unroll
    for (int nt = 0; nt < 8; ++nt) { f32x4 z = {0,0,0,0}; acc2[nt] = z; }
    #pragma unroll
    for (int kk = 0; kk < 2; ++kk) {
        int idxa = lr * N_WAY + ((kk * 32 + lg * 8) ^ ((lr & 7) << 3));
        bf16x8 af = *(const bf16x8*)&probs_s[wave][idxa];
        #pragma unroll
        for (int nt = 0; nt < 8; ++nt) {
            int d = nt * 16 + lr;
            int idxb = (d * N_WAY + kk * 32 + lg * 8) ^ ((d & 7) << 3);
            bf16x8 bf = *(const bf16x8*)&psT[idxb];
            acc2[nt] = __builtin_amdgcn_mfma_f32_16x16x32_bf16(af, bf, acc2[nt], 0, 0, 0);
        }
    }

    // ---- fused squared-error loss ---------------------------------------
    float lossacc = 0.0f;
    const long qgbase = (long)t * Q_QRY + qblk * QB + wave * 16;
    #pragma unroll
    for (int r = 0; r < 4; ++r) {
        const float* yrow = qy + (qgbase + lg * 4 + r) * D_EMB;
        #pragma unroll
        for (int nt = 0; nt < 8; ++nt) {
            float diff = acc2[nt][r] - yrow[nt * 16 + lr];
            lossacc += diff * diff;
        }
    }
    #pragma unroll
    for (int off = 32; off >= 1; off >>= 1) lossacc += __shfl_xor(lossacc, off);
    if (lane == 0) wloss[wave] = lossacc;
    __syncthreads();
    if (tid == 0)
        partials[blockIdx.x] = wloss[0] + wloss[1] + wloss[2] + wloss[3];
}

// ---------------------------------------------------------------------------
// Final reduce: 512 partials -> meta_loss scalar
// ---------------------------------------------------------------------------
__global__ __launch_bounds__(256) void reduce_kernel(
    const float* __restrict__ partials, float* __restrict__ out)
{
    __shared__ float wsum[4];
    const int tid = threadIdx.x;
    float s = partials[tid] + partials[tid + 256];
    #pragma unroll
    for (int off = 32; off >= 1; off >>= 1) s += __shfl_xor(s, off);
    if ((tid & 63) == 0) wsum[tid >> 6] = s;
    __syncthreads();
    if (tid == 0) {
        const float inv = 1.0f / ((float)T_TASKS * Q_QRY * D_EMB);
        out[0] = (wsum[0] + wsum[1] + wsum[2] + wsum[3]) * inv;
    }
}

extern "C" void kernel_launch(void* const* d_in, const int* in_sizes, int n_in,
                              void* d_out, int out_size, void* d_ws, size_t ws_size,
                              hipStream_t stream)
{
    const float* support_x = (const float*)d_in[0];
    const int*   support_ids = (const int*)d_in[1];
    const float* query_x  = (const float*)d_in[2];
    const float* query_y  = (const float*)d_in[3];
    const float* W1 = (const float*)d_in[4];
    const float* b1 = (const float*)d_in[5];
    const float* W2 = (const float*)d_in[6];
    const float* b2 = (const float*)d_in[7];

    float* ws = (float*)d_ws;
    float* se       = ws;                                        // 16*2048*128
    float* qe       = se + (long)T_TASKS * S_SUP * D_EMB;        // 16*2048*128
    float* protos   = qe + (long)T_TASKS * Q_QRY * D_EMB;        // 131072
    float* partials = protos + (long)T_TASKS * N_WAY * D_EMB;    // 1024 (512 used)
    ushortT* W1t    = (ushortT*)(partials + 1024);               // 512*256 bf16
    ushortT* W2t    = W1t + H_HID * D_IN;                        // 128*512 bf16
    float* psum     = (float*)(W2t + D_EMB * H_HID);             // 256*64*128
    int*   pcnt     = (int*)(psum + (long)T_TASKS * NCHUNK * N_WAY * D_EMB);

    const int rows_s = T_TASKS * S_SUP;   // 32768
    const int rows_q = T_TASKS * Q_QRY;   // 32768

    convert_weights<<<512, 256, 0, stream>>>(W1, W2, W1t, W2t);
    embed_mfma<<<rows_s / BM, 256, 0, stream>>>(support_x, W1t, b1, W2t, b2, se);
    embed_mfma<<<rows_q / BM, 256, 0, stream>>>(query_x,  W1t, b1, W2t, b2, qe);
    proto_partial<<<T_TASKS * NCHUNK, 256, 0, stream>>>(se, support_ids, psum, pcnt);
    proto_reduce<<<512, 256, 0, stream>>>(psum, pcnt, protos);
    query_mfma<<<T_TASKS * (Q_QRY / QB), 256, 0, stream>>>(qe, query_y, protos, partials);
    reduce_kernel<<<1, 256, 0, stream>>>(partials, (float*)d_out);
}

// Round 5
// 86.970 us; speedup vs baseline: 6.7666x; 1.5495x over previous
//
#include <hip/hip_runtime.h>
#include <hip/hip_bf16.h>

#define T_TASKS 16
#define S_SUP   2048
#define Q_QRY   2048
#define D_IN    256
#define H_HID   512
#define D_EMB   128
#define N_WAY   64
#define NCHUNK  16
#define CHUNK   128   // S_SUP / NCHUNK
#define QB      64    // queries per block in query_mfma
#define BM2     64    // rows per block in embed_mfma2

typedef unsigned short ushortT;
typedef unsigned int uintT;
using bf16x8 = __attribute__((ext_vector_type(8))) short;
using f32x4  = __attribute__((ext_vector_type(4))) float;

__device__ __forceinline__ ushortT f2b(float f) {
    uintT u = __builtin_bit_cast(uintT, f);
    uintT r = u + 0x7FFFu + ((u >> 16) & 1u);   // round-to-nearest-even
    return (ushortT)(r >> 16);
}
__device__ __forceinline__ float b2f(ushortT h) {
    return __builtin_bit_cast(float, (uintT)h << 16);
}

// ---------------------------------------------------------------------------
// Convert weights fp32 -> bf16, transposed to [N][K].
// ---------------------------------------------------------------------------
__global__ __launch_bounds__(256) void convert_weights(
    const float* __restrict__ W1, const float* __restrict__ W2,
    ushortT* __restrict__ W1t, ushortT* __restrict__ W2t)
{
    int i = blockIdx.x * 256 + threadIdx.x;
    if (i < D_IN * H_HID) {              // W1 [256][512] -> W1t [512][256]
        int k = i >> 9, n = i & 511;
        W1t[n * D_IN + k] = f2b(W1[i]);
    }
    if (i < H_HID * D_EMB) {             // W2 [512][128] -> W2t [128][512]
        int k = i >> 7, n = i & 127;
        W2t[n * H_HID + k] = f2b(W2[i]);
    }
}

// ---------------------------------------------------------------------------
// embed v2: 512 thr (8 waves), 64 rows/block, LDS overlay (xs inside hs buf).
// bid < 512 -> support rows, else query rows. Output bf16.
// Wave w: GEMM1 cols [w*64, w*64+64), GEMM2 cols [w*16, w*16+16).
// ---------------------------------------------------------------------------
__global__ __launch_bounds__(512, 4) void embed_mfma2(
    const float* __restrict__ xa, const float* __restrict__ xb,
    const ushortT* __restrict__ W1t, const float* __restrict__ b1,
    const ushortT* __restrict__ W2t, const float* __restrict__ b2,
    ushortT* __restrict__ outa, ushortT* __restrict__ outb)
{
    __shared__ ushortT buf[BM2 * H_HID];   // 64 KiB: xs (first 32K) then hs
    ushortT* xs = buf;                     // [64][256] swizzled
    ushortT* hs = buf;                     // [64][512] swizzled (overlay)

    const int tid  = threadIdx.x;
    const int wid  = tid >> 6;
    const int lane = tid & 63;
    const int lr   = lane & 15;
    const int lg   = lane >> 4;
    const int bid  = blockIdx.x;
    const float*  x   = (bid < 512) ? xa : xb;
    ushortT*      out = (bid < 512) ? outa : outb;
    const long rowbase = (long)(bid & 511) * BM2;

    // ---- stage x tile as bf16 into swizzled xs --------------------------
    #pragma unroll
    for (int i = 0; i < 4; ++i) {
        int ci   = tid + 512 * i;        // 2048 chunks of 8 elems
        int row  = ci >> 5;              // 32 chunks per row
        int col8 = (ci & 31) << 3;
        const float4* p = (const float4*)(x + (rowbase + row) * D_IN + col8);
        float4 a = p[0], b = p[1];
        uint4 v;
        v.x = (uintT)f2b(a.x) | ((uintT)f2b(a.y) << 16);
        v.y = (uintT)f2b(a.z) | ((uintT)f2b(a.w) << 16);
        v.z = (uintT)f2b(b.x) | ((uintT)f2b(b.y) << 16);
        v.w = (uintT)f2b(b.z) | ((uintT)f2b(b.w) << 16);
        int idx = (row << 8) + col8;
        idx ^= (row & 7) << 3;           // 16B-granular XOR swizzle
        *(uint4*)&xs[idx] = v;
    }
    __syncthreads();

    // ---- GEMM1: [64 x 256] @ W1t^T, wave strip of 64 cols ---------------
    f32x4 acc[4][4];                     // [m-tile][n-tile]
    #pragma unroll
    for (int n = 0; n < 4; ++n) {
        float bv = b1[wid * 64 + n * 16 + lr];
        f32x4 b4 = {bv, bv, bv, bv};
        #pragma unroll
        for (int m = 0; m < 4; ++m) acc[m][n] = b4;
    }
    {
        const ushortT* w1base = W1t + (wid * 64 + lr) * D_IN + lg * 8;
        #pragma unroll
        for (int kk = 0; kk < 8; ++kk) {
            bf16x8 af[4];
            #pragma unroll
            for (int m = 0; m < 4; ++m) {
                int row = m * 16 + lr;
                int idx = (row << 8) + kk * 32 + lg * 8;
                idx ^= (row & 7) << 3;
                af[m] = *(const bf16x8*)&xs[idx];
            }
            #pragma unroll
            for (int n = 0; n < 4; ++n) {
                bf16x8 bf = *(const bf16x8*)(w1base + (n * 16) * D_IN + kk * 32);
                #pragma unroll
                for (int m = 0; m < 4; ++m)
                    acc[m][n] = __builtin_amdgcn_mfma_f32_16x16x32_bf16(af[m], bf, acc[m][n], 0, 0, 0);
            }
        }
    }
    __syncthreads();   // all xs reads complete -> safe to overlay hs

    // ---- relu -> bf16 -> swizzled hs ------------------------------------
    #pragma unroll
    for (int m = 0; m < 4; ++m) {
        #pragma unroll
        for (int n = 0; n < 4; ++n) {
            int col = wid * 64 + n * 16 + lr;
            #pragma unroll
            for (int r = 0; r < 4; ++r) {
                int row = m * 16 + lg * 4 + r;
                float v = fmaxf(acc[m][n][r], 0.0f);
                int idx = row * H_HID + col;
                idx ^= (row & 7) << 3;
                hs[idx] = f2b(v);
            }
        }
    }
    __syncthreads();

    // ---- GEMM2: [64 x 512] @ W2t^T, wave strip of 16 cols ---------------
    f32x4 acc2[4];
    {
        float bv = b2[wid * 16 + lr];
        f32x4 b4 = {bv, bv, bv, bv};
        #pragma unroll
        for (int m = 0; m < 4; ++m) acc2[m] = b4;
    }
    {
        const ushortT* w2base = W2t + (wid * 16 + lr) * H_HID + lg * 8;
        #pragma unroll
        for (int kk = 0; kk < 16; ++kk) {
            bf16x8 bf = *(const bf16x8*)(w2base + kk * 32);
            #pragma unroll
            for (int m = 0; m < 4; ++m) {
                int row = m * 16 + lr;
                int idx = row * H_HID + kk * 32 + lg * 8;
                idx ^= (row & 7) << 3;
                bf16x8 af = *(const bf16x8*)&hs[idx];
                acc2[m] = __builtin_amdgcn_mfma_f32_16x16x32_bf16(af, bf, acc2[m], 0, 0, 0);
            }
        }
    }
    // ---- epilogue: bf16 out ---------------------------------------------
    #pragma unroll
    for (int m = 0; m < 4; ++m)
        #pragma unroll
        for (int r = 0; r < 4; ++r) {
            long row = rowbase + m * 16 + lg * 4 + r;
            out[row * D_EMB + wid * 16 + lr] = f2b(acc2[m][r]);
        }
}

// ---------------------------------------------------------------------------
// Proto phase 1: block = (t, chunk of 128 rows), two LDS accumulation streams.
// se is bf16 now; accumulate fp32.
// ---------------------------------------------------------------------------
__global__ __launch_bounds__(256) void proto_partial(
    const ushortT* __restrict__ se, const int* __restrict__ ids,
    float* __restrict__ psum, int* __restrict__ pcnt)
{
    __shared__ float acc[2][N_WAY][D_EMB];  // 64 KiB
    __shared__ int idbuf[CHUNK];

    const int tid  = threadIdx.x;
    const int t    = blockIdx.x >> 4;
    const int ch   = blockIdx.x & 15;
    const int d    = tid & 127;
    const int half = tid >> 7;

    #pragma unroll
    for (int i = 0; i < 64; ++i)
        ((float*)acc)[tid + 256 * i] = 0.0f;
    if (tid < CHUNK) idbuf[tid] = ids[t * S_SUP + ch * CHUNK + tid];
    __syncthreads();

    const ushortT* sb = se + ((long)t * S_SUP + ch * CHUNK) * D_EMB;
    #pragma unroll 4
    for (int s = 0; s < 64; ++s) {
        int row = half * 64 + s;
        int c = idbuf[row];
        acc[half][c][d] += b2f(sb[(long)row * D_EMB + d]);
    }
    __syncthreads();

    float* pb = psum + (long)blockIdx.x * N_WAY * D_EMB;
    #pragma unroll
    for (int i = 0; i < 32; ++i) {
        int idx = tid + 256 * i;
        pb[idx] = acc[0][idx >> 7][idx & 127] + acc[1][idx >> 7][idx & 127];
    }
    if (tid < N_WAY) {
        int cnt = 0;
        #pragma unroll 8
        for (int s = 0; s < CHUNK; ++s) cnt += (idbuf[s] == tid);
        pcnt[blockIdx.x * N_WAY + tid] = cnt;
    }
}

__global__ __launch_bounds__(256) void proto_reduce(
    const float* __restrict__ psum, const int* __restrict__ pcnt,
    float* __restrict__ protos)
{
    int idx = blockIdx.x * 256 + threadIdx.x;
    int t = idx >> 13;
    int cd = idx & 8191;
    int c = cd >> 7;

    float s = 0.0f;
    int cnt = 0;
    #pragma unroll
    for (int ch = 0; ch < NCHUNK; ++ch) {
        s   += psum[((long)(t * NCHUNK + ch)) * N_WAY * D_EMB + cd];
        cnt += pcnt[(t * NCHUNK + ch) * N_WAY + c];
    }
    protos[idx] = s / (float)(cnt > 0 ? cnt : 1);
}

// ---------------------------------------------------------------------------
// query_mfma: qe is bf16 now (direct fragment loads).
// ---------------------------------------------------------------------------
__global__ __launch_bounds__(256) void query_mfma(
    const ushortT* __restrict__ qe, const float* __restrict__ qy,
    const float* __restrict__ protos_g, float* __restrict__ partials)
{
    __shared__ ushortT psA[N_WAY * D_EMB];       // [c][d] swizzled, 16 KiB
    __shared__ ushortT psT[D_EMB * N_WAY];       // [d][c] swizzled, 16 KiB
    __shared__ ushortT probs_s[4][16 * N_WAY];   // per-wave [q][c] swizzled, 8 KiB
    __shared__ float p2s[N_WAY];
    __shared__ float wloss[4];

    const int tid  = threadIdx.x;
    const int wave = tid >> 6;
    const int lane = tid & 63;
    const int lr   = lane & 15;
    const int lg   = lane >> 4;
    const int t    = blockIdx.x >> 5;        // 32 blocks per task
    const int qblk = blockIdx.x & 31;

    const float* pt = protos_g + (long)t * N_WAY * D_EMB;

    // ---- stage psA [c][d] bf16 swizzled + per-chunk sumsq for p2 --------
    float pp[4];
    #pragma unroll
    for (int i = 0; i < 4; ++i) {
        int ci = tid + 256 * i;
        int c = ci >> 4, col8 = (ci & 15) << 3;
        const float4* p = (const float4*)(pt + c * D_EMB + col8);
        float4 a = p[0], b = p[1];
        ushortT h0 = f2b(a.x), h1 = f2b(a.y), h2 = f2b(a.z), h3 = f2b(a.w);
        ushortT h4 = f2b(b.x), h5 = f2b(b.y), h6 = f2b(b.z), h7 = f2b(b.w);
        float ss = b2f(h0)*b2f(h0) + b2f(h1)*b2f(h1) + b2f(h2)*b2f(h2) + b2f(h3)*b2f(h3)
                 + b2f(h4)*b2f(h4) + b2f(h5)*b2f(h5) + b2f(h6)*b2f(h6) + b2f(h7)*b2f(h7);
        pp[i] = ss;
        uint4 v;
        v.x = (uintT)h0 | ((uintT)h1 << 16);
        v.y = (uintT)h2 | ((uintT)h3 << 16);
        v.z = (uintT)h4 | ((uintT)h5 << 16);
        v.w = (uintT)h6 | ((uintT)h7 << 16);
        int idx = c * D_EMB + col8;
        idx ^= (c & 7) << 3;
        *(uint4*)&psA[idx] = v;
    }
    #pragma unroll
    for (int off = 1; off < 16; off <<= 1) {
        #pragma unroll
        for (int i = 0; i < 4; ++i) pp[i] += __shfl_xor(pp[i], off);
    }
    if ((lane & 15) == 0) {
        int a = wave * 4 + (lane >> 4);
        #pragma unroll
        for (int i = 0; i < 4; ++i) p2s[a + 16 * i] = pp[i];
    }

    // ---- stage psT [d][c] bf16 swizzled ---------------------------------
    {
        int d  = wave * 32 + (lane & 31);
        int ch = lane >> 5;
        #pragma unroll
        for (int m = 0; m < 4; ++m) {
            ushortT h[8];
            #pragma unroll
            for (int j = 0; j < 8; ++j)
                h[j] = f2b(pt[(ch * 32 + m * 8 + j) * D_EMB + d]);
            uint4 v;
            v.x = (uintT)h[0] | ((uintT)h[1] << 16);
            v.y = (uintT)h[2] | ((uintT)h[3] << 16);
            v.z = (uintT)h[4] | ((uintT)h[5] << 16);
            v.w = (uintT)h[6] | ((uintT)h[7] << 16);
            int idx = d * N_WAY + ch * 32 + m * 8;
            idx ^= (d & 7) << 3;
            *(uint4*)&psT[idx] = v;
        }
    }
    __syncthreads();

    // ---- load qe rows as B-frags (bf16 direct), compute q2 --------------
    const long qrow = (long)t * Q_QRY + qblk * QB + wave * 16 + lr;
    bf16x8 bq[4];
    float q2 = 0.0f;
    #pragma unroll
    for (int kk = 0; kk < 4; ++kk) {
        bq[kk] = *(const bf16x8*)(qe + qrow * D_EMB + kk * 32 + lg * 8);
        #pragma unroll
        for (int j = 0; j < 8; ++j) {
            float v = b2f((ushortT)bq[kk][j]);
            q2 += v * v;
        }
    }
    q2 += __shfl_xor(q2, 16);
    q2 += __shfl_xor(q2, 32);

    // ---- qpT = protos . qe^T --------------------------------------------
    f32x4 acc[4];
    #pragma unroll
    for (int mt = 0; mt < 4; ++mt) { f32x4 z = {0,0,0,0}; acc[mt] = z; }
    #pragma unroll
    for (int kk = 0; kk < 4; ++kk) {
        #pragma unroll
        for (int mt = 0; mt < 4; ++mt) {
            int c = mt * 16 + lr;
            int idx = (c * D_EMB + kk * 32 + lg * 8) ^ ((c & 7) << 3);
            bf16x8 af = *(const bf16x8*)&psA[idx];
            acc[mt] = __builtin_amdgcn_mfma_f32_16x16x32_bf16(af, bq[kk], acc[mt], 0, 0, 0);
        }
    }

    // ---- dist -> in-register softmax over 64 classes --------------------
    float ev[4][4];
    float mx = -1e30f;
    #pragma unroll
    for (int mt = 0; mt < 4; ++mt) {
        #pragma unroll
        for (int r = 0; r < 4; ++r) {
            int c = mt * 16 + lg * 4 + r;
            float d2 = q2 + p2s[c] - 2.0f * acc[mt][r];
            float v = -sqrtf(fmaxf(d2, 0.0f));
            ev[mt][r] = v;
            mx = fmaxf(mx, v);
        }
    }
    mx = fmaxf(mx, __shfl_xor(mx, 16));
    mx = fmaxf(mx, __shfl_xor(mx, 32));
    float sum = 0.0f;
    #pragma unroll
    for (int mt = 0; mt < 4; ++mt)
        #pragma unroll
        for (int r = 0; r < 4; ++r) {
            float e = __expf(ev[mt][r] - mx);
            ev[mt][r] = e;
            sum += e;
        }
    sum += __shfl_xor(sum, 16);
    sum += __shfl_xor(sum, 32);
    float inv = 1.0f / sum;

    // ---- probs -> per-wave LDS tile [q][c] bf16 swizzled ----------------
    #pragma unroll
    for (int mt = 0; mt < 4; ++mt) {
        uintT lo = (uintT)f2b(ev[mt][0] * inv) | ((uintT)f2b(ev[mt][1] * inv) << 16);
        uintT hi = (uintT)f2b(ev[mt][2] * inv) | ((uintT)f2b(ev[mt][3] * inv) << 16);
        int idx = lr * N_WAY + ((mt * 16 + lg * 4) ^ ((lr & 7) << 3));
        uint2 v = {lo, hi};
        *(uint2*)&probs_s[wave][idx] = v;
    }

    // ---- pred = probs . protos ------------------------------------------
    f32x4 acc2[8];
    #pragma unroll
    for (int nt = 0; nt < 8; ++nt) { f32x4 z = {0,0,0,0}; acc2[nt] = z; }
    #pragma unroll
    for (int kk = 0; kk < 2; ++kk) {
        int idxa = lr * N_WAY + ((kk * 32 + lg * 8) ^ ((lr & 7) << 3));
        bf16x8 af = *(const bf16x8*)&probs_s[wave][idxa];
        #pragma unroll
        for (int nt = 0; nt < 8; ++nt) {
            int d = nt * 16 + lr;
            int idxb = (d * N_WAY + kk * 32 + lg * 8) ^ ((d & 7) << 3);
            bf16x8 bf = *(const bf16x8*)&psT[idxb];
            acc2[nt] = __builtin_amdgcn_mfma_f32_16x16x32_bf16(af, bf, acc2[nt], 0, 0, 0);
        }
    }

    // ---- fused squared-error loss ---------------------------------------
    float lossacc = 0.0f;
    const long qgbase = (long)t * Q_QRY + qblk * QB + wave * 16;
    #pragma unroll
    for (int r = 0; r < 4; ++r) {
        const float* yrow = qy + (qgbase + lg * 4 + r) * D_EMB;
        #pragma unroll
        for (int nt = 0; nt < 8; ++nt) {
            float diff = acc2[nt][r] - yrow[nt * 16 + lr];
            lossacc += diff * diff;
        }
    }
    #pragma unroll
    for (int off = 32; off >= 1; off >>= 1) lossacc += __shfl_xor(lossacc, off);
    if (lane == 0) wloss[wave] = lossacc;
    __syncthreads();
    if (tid == 0)
        partials[blockIdx.x] = wloss[0] + wloss[1] + wloss[2] + wloss[3];
}

// ---------------------------------------------------------------------------
// Final reduce: 512 partials -> meta_loss scalar
// ---------------------------------------------------------------------------
__global__ __launch_bounds__(256) void reduce_kernel(
    const float* __restrict__ partials, float* __restrict__ out)
{
    __shared__ float wsum[4];
    const int tid = threadIdx.x;
    float s = partials[tid] + partials[tid + 256];
    #pragma unroll
    for (int off = 32; off >= 1; off >>= 1) s += __shfl_xor(s, off);
    if ((tid & 63) == 0) wsum[tid >> 6] = s;
    __syncthreads();
    if (tid == 0) {
        const float inv = 1.0f / ((float)T_TASKS * Q_QRY * D_EMB);
        out[0] = (wsum[0] + wsum[1] + wsum[2] + wsum[3]) * inv;
    }
}

extern "C" void kernel_launch(void* const* d_in, const int* in_sizes, int n_in,
                              void* d_out, int out_size, void* d_ws, size_t ws_size,
                              hipStream_t stream)
{
    const float* support_x = (const float*)d_in[0];
    const int*   support_ids = (const int*)d_in[1];
    const float* query_x  = (const float*)d_in[2];
    const float* query_y  = (const float*)d_in[3];
    const float* W1 = (const float*)d_in[4];
    const float* b1 = (const float*)d_in[5];
    const float* W2 = (const float*)d_in[6];
    const float* b2 = (const float*)d_in[7];

    ushortT* se     = (ushortT*)d_ws;                            // 4.19M bf16
    ushortT* qe     = se + (long)T_TASKS * S_SUP * D_EMB;        // 4.19M bf16
    float* protos   = (float*)(qe + (long)T_TASKS * Q_QRY * D_EMB); // 131072 f
    float* partials = protos + T_TASKS * N_WAY * D_EMB;          // 1024
    ushortT* W1t    = (ushortT*)(partials + 1024);               // 512*256 bf16
    ushortT* W2t    = W1t + H_HID * D_IN;                        // 128*512 bf16
    float* psum     = (float*)(W2t + D_EMB * H_HID);             // 256*64*128 f
    int*   pcnt     = (int*)(psum + (long)T_TASKS * NCHUNK * N_WAY * D_EMB);

    convert_weights<<<512, 256, 0, stream>>>(W1, W2, W1t, W2t);
    embed_mfma2<<<1024, 512, 0, stream>>>(support_x, query_x, W1t, b1, W2t, b2, se, qe);
    proto_partial<<<T_TASKS * NCHUNK, 256, 0, stream>>>(se, support_ids, psum, pcnt);
    proto_reduce<<<512, 256, 0, stream>>>(psum, pcnt, protos);
    query_mfma<<<T_TASKS * (Q_QRY / QB), 256, 0, stream>>>(qe, query_y, protos, partials);
    reduce_kernel<<<1, 256, 0, stream>>>(partials, (float*)d_out);
}